// Round 5
// baseline (1434.267 us; speedup 1.0000x reference)
//
#include <hip/hip_runtime.h>

#define FDIM 64
#define CHUNK 16384      // edges per multisplit block (1024 threads x 16)
#define MAXBUCK 2048     // LDS bound: supports 2N <= 262144
#define BSEG 128         // segments per bucket (w >> 7)

typedef __attribute__((ext_vector_type(8))) short short8;
typedef __attribute__((ext_vector_type(4))) float f32x4;

__device__ __forceinline__ ushort f2bf(float f) {
    unsigned u = __float_as_uint(f);
    unsigned r = (u + 0x7FFF + ((u >> 16) & 1)) >> 16;   // RNE
    return (ushort)r;
}
__device__ __forceinline__ float b2f(ushort s) {
    return __uint_as_float(((unsigned)s) << 16);
}

// ============ prep: x (f32) -> U[:,64:128) (bf16). U rows are 192 bf16. =====
__global__ __launch_bounds__(256) void prep_kernel(
    const float* __restrict__ x, int N, ushort* __restrict__ U)
{
    int i4 = (blockIdx.x * 256 + threadIdx.x) * 4;
    if (i4 >= N * 64) return;
    float4 f = *(const float4*)&x[i4];
    int node = i4 >> 6, c = i4 & 63;
    ushort4 s;
    s.x = f2bf(f.x); s.y = f2bf(f.y); s.z = f2bf(f.z); s.w = f2bf(f.w);
    *(ushort4*)&U[(size_t)node * 192 + 64 + c] = s;
}

// ============ K2: per-block bucket histogram over BOTH edge lists ===========
// Unified edge index i in [0,2E): i<E -> pos list, else neg (w = N + dst).
__global__ __launch_bounds__(1024) void hist_bucket_kernel(
    const int* __restrict__ pei, const int* __restrict__ nei, int E, int N,
    int nbuck, int* __restrict__ cntA)
{
    __shared__ int hist[MAXBUCK];
    int t = threadIdx.x;
    for (int i = t; i < MAXBUCK; i += 1024) hist[i] = 0;
    __syncthreads();
    int base = blockIdx.x * CHUNK;
    for (int j = t; j < CHUNK; j += 1024) {
        int i = base + j;
        if (i < 2 * E) {
            int w;
            if (i < E) w = pei[E + i];
            else       w = N + nei[E + (i - E)];
            atomicAdd(&hist[w >> 7], 1);
        }
    }
    __syncthreads();
    int row = blockIdx.x * nbuck;
    for (int b = t; b < nbuck; b += 1024) cntA[row + b] = hist[b];
}

// ============ K3a: exclusive column scan of cntA (in place) =================
__global__ __launch_bounds__(256) void colscan_kernel(
    int* __restrict__ cntA, int nA, int nbuck, int* __restrict__ colsum)
{
    int b = blockIdx.x * 256 + threadIdx.x;
    if (b >= nbuck) return;
    int run = 0;
    #pragma unroll 4
    for (int a = 0; a < nA; ++a) {
        int v = cntA[(size_t)a * nbuck + b];
        cntA[(size_t)a * nbuck + b] = run;
        run += v;
    }
    colsum[b] = run;
}

// ============ K3b: exclusive scan over bucket sums -> bstart[0..nbuck] ======
__global__ __launch_bounds__(256) void scan_buckets_kernel(
    const int* __restrict__ colsum, int* __restrict__ bstart, int nbuck)
{
    __shared__ int s[256];
    int t = threadIdx.x;
    int vals[8]; int sum = 0;
    #pragma unroll
    for (int r = 0; r < 8; ++r) {
        int idx = t * 8 + r;
        vals[r] = (idx < nbuck) ? colsum[idx] : 0;
        sum += vals[r];
    }
    s[t] = sum;
    __syncthreads();
    for (int d = 1; d < 256; d <<= 1) {
        int v = (t >= d) ? s[t - d] : 0;
        __syncthreads();
        s[t] += v;
        __syncthreads();
    }
    int run = s[t] - sum;
    #pragma unroll
    for (int r = 0; r < 8; ++r) {
        int idx = t * 8 + r;
        if (idx < nbuck) bstart[idx] = run;
        run += vals[r];
    }
    if (t == 255) bstart[nbuck] = s[255];
}

// ============ K4: place packed (src | wlocal<<17) into bucket-grouped P =====
__global__ __launch_bounds__(1024) void place_bucket_kernel(
    const int* __restrict__ pei, const int* __restrict__ nei, int E, int N,
    int nbuck, const int* __restrict__ cntA, const int* __restrict__ bstart,
    unsigned* __restrict__ P)
{
    __shared__ int cur[MAXBUCK];
    int t = threadIdx.x;
    int row = blockIdx.x * nbuck;
    for (int b = t; b < nbuck; b += 1024) cur[b] = bstart[b] + cntA[row + b];
    __syncthreads();
    int base = blockIdx.x * CHUNK;
    for (int j = t; j < CHUNK; j += 1024) {
        int i = base + j;
        if (i < 2 * E) {
            int src, w;
            if (i < E) { src = pei[i]; w = pei[E + i]; }
            else       { int e = i - E; src = nei[e]; w = N + nei[E + e]; }
            int slot = atomicAdd(&cur[w >> 7], 1);
            P[slot] = (unsigned)src | ((unsigned)(w & 127) << 17);
        }
    }
}

// ============ K5: one block per bucket; LDS f32 accumulate; write bf16 mean =
__global__ __launch_bounds__(256) void agg_lds_kernel(
    const unsigned* __restrict__ P, const int* __restrict__ bstart,
    int N, ushort* __restrict__ U)
{
    __shared__ float accf[BSEG][64];   // 32 KB
    __shared__ int deg[BSEG];

    int t = threadIdx.x;
    int lane = t & 63;
    int wid = t >> 6;
    int b = blockIdx.x;

    for (int i = t; i < BSEG * 64; i += 256) accf[i >> 6][i & 63] = 0.f;
    if (t < BSEG) deg[t] = 0;
    __syncthreads();

    int start = bstart[b];
    int end = bstart[b + 1];

    for (int base = start + wid * 64; base < end; base += 256) {
        int myi = base + lane;
        unsigned p = 0;
        if (myi < end) {
            p = P[myi];
            atomicAdd(&deg[p >> 17], 1);
        }
        int cnt = end - base; if (cnt > 64) cnt = 64;
        if (cnt == 64) {
            #pragma unroll 8
            for (int j = 0; j < 64; ++j) {
                unsigned pj = (unsigned)__shfl((int)p, j);
                int src = (int)(pj & 0x1FFFFu);
                int wl  = (int)(pj >> 17);
                float v = b2f(U[(size_t)src * 192 + 64 + lane]);
                atomicAdd(&accf[wl][lane], v);
            }
        } else {
            for (int j = 0; j < cnt; ++j) {
                unsigned pj = (unsigned)__shfl((int)p, j);
                int src = (int)(pj & 0x1FFFFu);
                int wl  = (int)(pj >> 17);
                float v = b2f(U[(size_t)src * 192 + 64 + lane]);
                atomicAdd(&accf[wl][lane], v);
            }
        }
    }
    __syncthreads();

    // write means: 128 segs x 64 feats as ushort4 (2048 x 4-chunks)
    int twoN = 2 * N;
    for (int i = t; i < BSEG * 16; i += 256) {
        int wl = i >> 4, c0 = (i & 15) * 4;
        int w = (b << 7) + wl;
        if (w < twoN) {
            int node = (w < N) ? w : (w - N);
            int colbase = (w < N) ? 0 : 128;
            float d = 1.0f / fmaxf((float)deg[wl], 1.0f);
            ushort4 s;
            s.x = f2bf(accf[wl][c0 + 0] * d);
            s.y = f2bf(accf[wl][c0 + 1] * d);
            s.z = f2bf(accf[wl][c0 + 2] * d);
            s.w = f2bf(accf[wl][c0 + 3] * d);
            *(ushort4*)&U[(size_t)node * 192 + colbase + c0] = s;
        }
    }
}

// ============ MFMA transform: out = U-slices @ G + bias =====================
// U row = [aggp(0:64) | x(64:128) | aggn(128:192)] bf16.
// nh=0: out[:,0:64]  = U[:,0:128)  @ [Wp.T ; Wpc.T] + bp
// nh=1: out[:,64:128]= U[:,64:192) @ [Wnc.T; Wn.T ] + bn
__global__ __launch_bounds__(256) void transform_mfma_kernel(
    const ushort* __restrict__ U,
    const float* __restrict__ Wp, const float* __restrict__ Wpc, const float* __restrict__ bp,
    const float* __restrict__ Wn, const float* __restrict__ Wnc, const float* __restrict__ bn,
    int N, int ntiles, float* __restrict__ out)
{
    __shared__ __align__(16) ushort A[64][200];

    int t = threadIdx.x;
    int lane = t & 63;
    int w = t >> 6;
    int mh = w >> 1;
    int nh = w & 1;
    int r16 = lane & 15;
    int q = lane >> 4;

    const float* W0 = nh ? Wnc : Wp;
    const float* W1 = nh ? Wn  : Wpc;
    short8 bfrag[4][4];
    #pragma unroll
    for (int ki = 0; ki < 4; ++ki) {
        const float* Wsel = (ki < 2) ? W0 : W1;
        int kk = (ki * 32 + q * 8) & 63;
        #pragma unroll
        for (int ni = 0; ni < 4; ++ni) {
            int n = ni * 16 + r16;
            float4 f0 = *(const float4*)&Wsel[n * 64 + kk];
            float4 f1 = *(const float4*)&Wsel[n * 64 + kk + 4];
            short8 s;
            s[0] = (short)f2bf(f0.x); s[1] = (short)f2bf(f0.y);
            s[2] = (short)f2bf(f0.z); s[3] = (short)f2bf(f0.w);
            s[4] = (short)f2bf(f1.x); s[5] = (short)f2bf(f1.y);
            s[6] = (short)f2bf(f1.z); s[7] = (short)f2bf(f1.w);
            bfrag[ki][ni] = s;
        }
    }
    const float* bsel = nh ? bn : bp;
    float bias[4];
    #pragma unroll
    for (int ni = 0; ni < 4; ++ni) bias[ni] = bsel[ni * 16 + r16];

    int kbase = nh * 64;

    for (int tile = blockIdx.x; tile < ntiles; tile += gridDim.x) {
        int node0 = tile * 64;
        __syncthreads();
        for (int i = t; i < 64 * 24; i += 256) {
            int row = i / 24, c = i % 24;
            int node = node0 + row;
            if (node >= N) node = N - 1;
            *(int4*)&A[row][c * 8] = *(const int4*)&U[(size_t)node * 192 + c * 8];
        }
        __syncthreads();

        f32x4 acc[2][4];
        #pragma unroll
        for (int mi = 0; mi < 2; ++mi)
            #pragma unroll
            for (int ni = 0; ni < 4; ++ni) {
                f32x4 c4 = {bias[ni], bias[ni], bias[ni], bias[ni]};
                acc[mi][ni] = c4;
            }

        #pragma unroll
        for (int ki = 0; ki < 4; ++ki) {
            short8 a0 = *(const short8*)&A[mh * 32 + r16][kbase + ki * 32 + q * 8];
            short8 a1 = *(const short8*)&A[mh * 32 + 16 + r16][kbase + ki * 32 + q * 8];
            #pragma unroll
            for (int ni = 0; ni < 4; ++ni) {
                acc[0][ni] = __builtin_amdgcn_mfma_f32_16x16x32_bf16(
                    a0, bfrag[ki][ni], acc[0][ni], 0, 0, 0);
                acc[1][ni] = __builtin_amdgcn_mfma_f32_16x16x32_bf16(
                    a1, bfrag[ki][ni], acc[1][ni], 0, 0, 0);
            }
        }

        #pragma unroll
        for (int mi = 0; mi < 2; ++mi)
            #pragma unroll
            for (int ni = 0; ni < 4; ++ni)
                #pragma unroll
                for (int r = 0; r < 4; ++r) {
                    int node = node0 + mh * 32 + mi * 16 + q * 4 + r;
                    if (node < N)
                        out[(size_t)node * 128 + nh * 64 + ni * 16 + r16] =
                            acc[mi][ni][r];
                }
    }
}

// ===================== f32 fallback path (small ws / big N) =================
__global__ __launch_bounds__(256) void scatter_kernel(
    const int* __restrict__ ei, int E, const float* __restrict__ x,
    float* __restrict__ out, int col_off, float* __restrict__ cnt)
{
    long long gid = (long long)blockIdx.x * 256 + threadIdx.x;
    int e = (int)(gid >> 6);
    if (e >= E) return;
    int f = (int)(gid & 63);
    int s = ei[e], d = ei[E + e];
    atomicAdd(&out[d * 128 + col_off + f], x[s * FDIM + f]);
    if (f == 0) atomicAdd(&cnt[d], 1.0f);
}

__global__ __launch_bounds__(256) void scale_kernel(
    float* __restrict__ out, const float* __restrict__ cnt, int N)
{
    int idx = blockIdx.x * 256 + threadIdx.x;
    if (idx >= N * 128) return;
    int node = idx >> 7, col = idx & 127, half = col >> 6;
    out[idx] /= fmaxf(cnt[half * N + node], 1.f);
}

__global__ __launch_bounds__(256) void transform_f32_kernel(
    const float* __restrict__ x,
    const float* __restrict__ Wp, const float* __restrict__ Wpc, const float* __restrict__ bp,
    const float* __restrict__ Wn, const float* __restrict__ Wnc, const float* __restrict__ bn,
    int N, float* __restrict__ out)
{
    __shared__ float V[2][128][64];
    __shared__ float B[192][36];
    __shared__ float bias[128];
    int t = threadIdx.x;
    int node0 = blockIdx.x * 32;
    for (int i = t; i < 4096; i += 256) {
        int k = i >> 6, j = i & 63;
        V[0][k][j]      = Wp[j * 64 + k];
        V[0][64 + k][j] = Wpc[j * 64 + k];
        V[1][k][j]      = Wnc[j * 64 + k];
        V[1][64 + k][j] = Wn[j * 64 + k];
    }
    if (t < 64) { bias[t] = bp[t]; bias[64 + t] = bn[t]; }
    for (int i = t; i < 64 * 32; i += 256) {
        int k = i & 63, n = i >> 6;
        int node = node0 + n;
        if (node < N) {
            B[k][n]       = out[(size_t)node * 128 + k];
            B[64 + k][n]  = x[node * 64 + k];
            B[128 + k][n] = out[(size_t)node * 128 + 64 + k];
        }
    }
    __syncthreads();
    int jj = t & 31, nq = t >> 5;
    float acc[2][4][2];
    for (int h = 0; h < 2; ++h)
        for (int i = 0; i < 4; ++i) { acc[h][i][0] = 0.f; acc[h][i][1] = 0.f; }
    for (int h = 0; h < 2; ++h) {
        int browbase = h * 64;
        #pragma unroll 4
        for (int kk = 0; kk < 128; ++kk) {
            float2 v = *(const float2*)&V[h][kk][2 * jj];
            float4 b = *(const float4*)&B[browbase + kk][4 * nq];
            acc[h][0][0] += b.x * v.x;  acc[h][0][1] += b.x * v.y;
            acc[h][1][0] += b.y * v.x;  acc[h][1][1] += b.y * v.y;
            acc[h][2][0] += b.z * v.x;  acc[h][2][1] += b.z * v.y;
            acc[h][3][0] += b.w * v.x;  acc[h][3][1] += b.w * v.y;
        }
    }
    for (int h = 0; h < 2; ++h) {
        float bx = bias[h * 64 + 2 * jj], by = bias[h * 64 + 2 * jj + 1];
        for (int i = 0; i < 4; ++i) {
            int node = node0 + 4 * nq + i;
            if (node < N) {
                float2 r; r.x = acc[h][i][0] + bx; r.y = acc[h][i][1] + by;
                *(float2*)&out[(size_t)node * 128 + h * 64 + 2 * jj] = r;
            }
        }
    }
}

// ============================================================================
extern "C" void kernel_launch(void* const* d_in, const int* in_sizes, int n_in,
                              void* d_out, int out_size, void* d_ws, size_t ws_size,
                              hipStream_t stream) {
    const float* x   = (const float*)d_in[0];
    const int*   pei = (const int*)d_in[1];
    const int*   nei = (const int*)d_in[2];
    const float* Wp  = (const float*)d_in[3];
    const float* Wpc = (const float*)d_in[4];
    const float* bp  = (const float*)d_in[5];
    const float* Wn  = (const float*)d_in[6];
    const float* Wnc = (const float*)d_in[7];
    const float* bn  = (const float*)d_in[8];
    float* out = (float*)d_out;

    int N = in_sizes[0] / FDIM;
    int E = in_sizes[1] / 2;
    int twoE = 2 * E;
    int nbuck = (2 * N + BSEG - 1) / BSEG;
    int nA = (twoE + CHUNK - 1) / CHUNK;

    // ws layout (ints): cntA[nA*nbuck] | colsum[nbuck] | bstart[nbuck+1] | P[2E] | U
    size_t ints = (size_t)nA * nbuck + nbuck + (nbuck + 1) + twoE;
    size_t U_off = ((ints * 4 + 15) / 16) * 16;
    size_t need = U_off + (size_t)N * 192 * 2;

    if (ws_size >= need && nbuck <= MAXBUCK && N <= (1 << 17)) {
        int* cntA    = (int*)d_ws;
        int* colsum  = cntA + (size_t)nA * nbuck;
        int* bstart  = colsum + nbuck;
        unsigned* P  = (unsigned*)(bstart + nbuck + 1);
        ushort* U    = (ushort*)((char*)d_ws + U_off);

        prep_kernel<<<(N * 64 / 4 + 255) / 256, 256, 0, stream>>>(x, N, U);

        hist_bucket_kernel<<<nA, 1024, 0, stream>>>(pei, nei, E, N, nbuck, cntA);
        colscan_kernel<<<(nbuck + 255) / 256, 256, 0, stream>>>(cntA, nA, nbuck, colsum);
        scan_buckets_kernel<<<1, 256, 0, stream>>>(colsum, bstart, nbuck);
        place_bucket_kernel<<<nA, 1024, 0, stream>>>(pei, nei, E, N, nbuck, cntA, bstart, P);

        agg_lds_kernel<<<nbuck, 256, 0, stream>>>(P, bstart, N, U);

        int ntiles = (N + 63) / 64;
        transform_mfma_kernel<<<768, 256, 0, stream>>>(
            U, Wp, Wpc, bp, Wn, Wnc, bn, N, ntiles, out);
    } else {
        float* cntf = (float*)d_ws;
        hipMemsetAsync(d_out, 0, (size_t)out_size * sizeof(float), stream);
        hipMemsetAsync(d_ws, 0, (size_t)2 * N * sizeof(float), stream);
        int sblocks = (int)(((long long)E * 64 + 255) / 256);
        scatter_kernel<<<sblocks, 256, 0, stream>>>(pei, E, x, out, 0, cntf);
        scatter_kernel<<<sblocks, 256, 0, stream>>>(nei, E, x, out, 64, cntf + N);
        scale_kernel<<<(N * 128 + 255) / 256, 256, 0, stream>>>(out, cntf, N);
        transform_f32_kernel<<<(N + 31) / 32, 256, 0, stream>>>(
            x, Wp, Wpc, bp, Wn, Wnc, bn, N, out);
    }
}

// Round 6
// 357.452 us; speedup vs baseline: 4.0125x; 4.0125x over previous
//
#include <hip/hip_runtime.h>

#define FDIM 64
#define CHUNK 16384      // edges per multisplit block (1024 threads x 16)
#define MAXBUCK 2048     // LDS bound: supports 2N <= 262144
#define BSEG 128         // segments per bucket (w >> 7)
#define MAXE 4608        // max edges per bucket handled by LDS sort (2.25x mean)
#define DEGFLAG (1u << 30)

typedef __attribute__((ext_vector_type(8))) short short8;
typedef __attribute__((ext_vector_type(4))) float f32x4;

__device__ __forceinline__ ushort f2bf(float f) {
    unsigned u = __float_as_uint(f);
    unsigned r = (u + 0x7FFF + ((u >> 16) & 1)) >> 16;   // RNE
    return (ushort)r;
}
__device__ __forceinline__ float b2f(ushort s) {
    return __uint_as_float(((unsigned)s) << 16);
}

// ============ prep: x (f32) -> U[:,64:128) (bf16). U rows are 192 bf16. =====
__global__ __launch_bounds__(256) void prep_kernel(
    const float* __restrict__ x, int N, ushort* __restrict__ U)
{
    int i4 = (blockIdx.x * 256 + threadIdx.x) * 4;
    if (i4 >= N * 64) return;
    float4 f = *(const float4*)&x[i4];
    int node = i4 >> 6, c = i4 & 63;
    ushort4 s;
    s.x = f2bf(f.x); s.y = f2bf(f.y); s.z = f2bf(f.z); s.w = f2bf(f.w);
    *(ushort4*)&U[(size_t)node * 192 + 64 + c] = s;
}

// ============ K2: per-block bucket histogram over BOTH edge lists ===========
__global__ __launch_bounds__(1024) void hist_bucket_kernel(
    const int* __restrict__ pei, const int* __restrict__ nei, int E, int N,
    int nbuck, int* __restrict__ cntA)
{
    __shared__ int hist[MAXBUCK];
    int t = threadIdx.x;
    for (int i = t; i < MAXBUCK; i += 1024) hist[i] = 0;
    __syncthreads();
    int base = blockIdx.x * CHUNK;
    for (int j = t; j < CHUNK; j += 1024) {
        int i = base + j;
        if (i < 2 * E) {
            int w;
            if (i < E) w = pei[E + i];
            else       w = N + nei[E + (i - E)];
            atomicAdd(&hist[w >> 7], 1);
        }
    }
    __syncthreads();
    int row = blockIdx.x * nbuck;
    for (int b = t; b < nbuck; b += 1024) cntA[row + b] = hist[b];
}

// ============ K3a: exclusive column scan of cntA (in place) =================
__global__ __launch_bounds__(256) void colscan_kernel(
    int* __restrict__ cntA, int nA, int nbuck, int* __restrict__ colsum)
{
    int b = blockIdx.x * 256 + threadIdx.x;
    if (b >= nbuck) return;
    int run = 0;
    #pragma unroll 4
    for (int a = 0; a < nA; ++a) {
        int v = cntA[(size_t)a * nbuck + b];
        cntA[(size_t)a * nbuck + b] = run;
        run += v;
    }
    colsum[b] = run;
}

// ============ K3b: exclusive scan over bucket sums -> bstart[0..nbuck] ======
__global__ __launch_bounds__(256) void scan_buckets_kernel(
    const int* __restrict__ colsum, int* __restrict__ bstart, int nbuck)
{
    __shared__ int s[256];
    int t = threadIdx.x;
    int vals[8]; int sum = 0;
    #pragma unroll
    for (int r = 0; r < 8; ++r) {
        int idx = t * 8 + r;
        vals[r] = (idx < nbuck) ? colsum[idx] : 0;
        sum += vals[r];
    }
    s[t] = sum;
    __syncthreads();
    for (int d = 1; d < 256; d <<= 1) {
        int v = (t >= d) ? s[t - d] : 0;
        __syncthreads();
        s[t] += v;
        __syncthreads();
    }
    int run = s[t] - sum;
    #pragma unroll
    for (int r = 0; r < 8; ++r) {
        int idx = t * 8 + r;
        if (idx < nbuck) bstart[idx] = run;
        run += vals[r];
    }
    if (t == 255) bstart[nbuck] = s[255];
}

// ============ K4: place packed (src | wlocal<<17) into bucket-grouped P =====
__global__ __launch_bounds__(1024) void place_bucket_kernel(
    const int* __restrict__ pei, const int* __restrict__ nei, int E, int N,
    int nbuck, const int* __restrict__ cntA, const int* __restrict__ bstart,
    unsigned* __restrict__ P)
{
    __shared__ int cur[MAXBUCK];
    int t = threadIdx.x;
    int row = blockIdx.x * nbuck;
    for (int b = t; b < nbuck; b += 1024) cur[b] = bstart[b] + cntA[row + b];
    __syncthreads();
    int base = blockIdx.x * CHUNK;
    for (int j = t; j < CHUNK; j += 1024) {
        int i = base + j;
        if (i < 2 * E) {
            int src, w;
            if (i < E) { src = pei[i]; w = pei[E + i]; }
            else       { int e = i - E; src = nei[e]; w = N + nei[E + e]; }
            int slot = atomicAdd(&cur[w >> 7], 1);
            P[slot] = (unsigned)src | ((unsigned)(w & 127) << 17);
        }
    }
}

// ============ K5: within-bucket counting sort -> per-segment CSR ============
// Normal buckets (cnt<=MAXE): P slice rewritten in place as plain src ints,
// sorted by segment; soffs/sdeg give per-segment CSR.
// Overflow buckets: P left packed; sdeg flagged; agg scan-filters the bucket.
__global__ __launch_bounds__(256) void sort_bucket_kernel(
    unsigned* __restrict__ P, const int* __restrict__ bstart,
    int twoN, int* __restrict__ soffs, int* __restrict__ sdeg)
{
    __shared__ unsigned tmp[MAXE];
    __shared__ int sorted_[MAXE];
    __shared__ int hist[BSEG], off[BSEG], cur[BSEG];

    int t = threadIdx.x;
    int b = blockIdx.x;
    int start = bstart[b], end = bstart[b + 1];
    int cnt = end - start;

    if (t < BSEG) hist[t] = 0;
    __syncthreads();

    if (cnt <= MAXE) {
        for (int i = t; i < cnt; i += 256) {
            unsigned p = P[start + i];
            tmp[i] = p;
            atomicAdd(&hist[p >> 17], 1);
        }
        __syncthreads();
        // exclusive scan of hist over 128 bins
        if (t < BSEG) off[t] = hist[t];
        __syncthreads();
        for (int d = 1; d < BSEG; d <<= 1) {
            int v = 0;
            if (t < BSEG && t >= d) v = off[t - d];
            __syncthreads();
            if (t < BSEG) off[t] += v;
            __syncthreads();
        }
        if (t < BSEG) {
            int excl = off[t] - hist[t];
            cur[t] = excl;
            int w = (b << 7) + t;
            if (w < twoN) { soffs[w] = start + excl; sdeg[w] = hist[t]; }
        }
        __syncthreads();
        for (int i = t; i < cnt; i += 256) {
            unsigned p = tmp[i];
            int slot = atomicAdd(&cur[p >> 17], 1);
            sorted_[slot] = (int)(p & 0x1FFFFu);
        }
        __syncthreads();
        for (int i = t; i < cnt; i += 256) P[start + i] = (unsigned)sorted_[i];
    } else {
        // overflow: histogram only; leave P packed, flag segments
        for (int i = start + t; i < end; i += 256) atomicAdd(&hist[P[i] >> 17], 1);
        __syncthreads();
        if (t < BSEG) {
            int w = (b << 7) + t;
            if (w < twoN) { soffs[w] = start; sdeg[w] = hist[t] | (int)DEGFLAG; }
        }
    }
}

// ============ K6: one wave per segment; 4 edges x 16 lanes x ushort4 gather =
__global__ __launch_bounds__(256) void agg_wide_kernel(
    const unsigned* __restrict__ P, const int* __restrict__ soffs,
    const int* __restrict__ sdeg, const int* __restrict__ bstart,
    int N, ushort* __restrict__ U)
{
    int w = blockIdx.x * 4 + (threadIdx.x >> 6);
    if (w >= 2 * N) return;
    int lane = threadIdx.x & 63;
    int g = lane >> 4;        // edge slot within group of 4
    int r = lane & 15;        // feature quad: feats 4r..4r+3

    int draw = sdeg[w];
    int deg = draw & 0x3FFFFFFF;
    float4 acc = {0.f, 0.f, 0.f, 0.f};

    if ((draw & (int)DEGFLAG) == 0) {
        // sorted CSR: P holds plain src ints
        int o = soffs[w];
        int endv = o + deg;
        int i = o;
        #pragma unroll 2
        for (; i + 4 <= endv; i += 4) {
            int src = (int)P[i + g];
            ushort4 u = *(const ushort4*)&U[(size_t)src * 192 + 64 + 4 * r];
            acc.x += b2f(u.x); acc.y += b2f(u.y);
            acc.z += b2f(u.z); acc.w += b2f(u.w);
        }
        int rem = endv - i;
        if (g < rem) {
            int src = (int)P[i + g];
            ushort4 u = *(const ushort4*)&U[(size_t)src * 192 + 64 + 4 * r];
            acc.x += b2f(u.x); acc.y += b2f(u.y);
            acc.z += b2f(u.z); acc.w += b2f(u.w);
        }
    } else {
        // overflow bucket: scan-filter packed entries
        int b = w >> 7;
        int wl = w & 127;
        int bs = bstart[b], be = bstart[b + 1];
        for (int i = bs; i < be; i += 4) {
            int idx = i + g;
            if (idx < be) {
                unsigned p = P[idx];
                if ((int)(p >> 17) == wl) {
                    int src = (int)(p & 0x1FFFFu);
                    ushort4 u = *(const ushort4*)&U[(size_t)src * 192 + 64 + 4 * r];
                    acc.x += b2f(u.x); acc.y += b2f(u.y);
                    acc.z += b2f(u.z); acc.w += b2f(u.w);
                }
            }
        }
    }

    // reduce across the 4 edge-groups (lanes g=0..3 share feature quad r)
    acc.x += __shfl_xor(acc.x, 16); acc.x += __shfl_xor(acc.x, 32);
    acc.y += __shfl_xor(acc.y, 16); acc.y += __shfl_xor(acc.y, 32);
    acc.z += __shfl_xor(acc.z, 16); acc.z += __shfl_xor(acc.z, 32);
    acc.w += __shfl_xor(acc.w, 16); acc.w += __shfl_xor(acc.w, 32);

    if (g == 0) {
        int node = (w < N) ? w : (w - N);
        int colbase = (w < N) ? 0 : 128;
        float d = 1.0f / fmaxf((float)deg, 1.0f);
        ushort4 s;
        s.x = f2bf(acc.x * d); s.y = f2bf(acc.y * d);
        s.z = f2bf(acc.z * d); s.w = f2bf(acc.w * d);
        *(ushort4*)&U[(size_t)node * 192 + colbase + 4 * r] = s;
    }
}

// ============ MFMA transform: out = U-slices @ G + bias =====================
__global__ __launch_bounds__(256) void transform_mfma_kernel(
    const ushort* __restrict__ U,
    const float* __restrict__ Wp, const float* __restrict__ Wpc, const float* __restrict__ bp,
    const float* __restrict__ Wn, const float* __restrict__ Wnc, const float* __restrict__ bn,
    int N, int ntiles, float* __restrict__ out)
{
    __shared__ __align__(16) ushort A[64][200];

    int t = threadIdx.x;
    int lane = t & 63;
    int w = t >> 6;
    int mh = w >> 1;
    int nh = w & 1;
    int r16 = lane & 15;
    int q = lane >> 4;

    const float* W0 = nh ? Wnc : Wp;
    const float* W1 = nh ? Wn  : Wpc;
    short8 bfrag[4][4];
    #pragma unroll
    for (int ki = 0; ki < 4; ++ki) {
        const float* Wsel = (ki < 2) ? W0 : W1;
        int kk = (ki * 32 + q * 8) & 63;
        #pragma unroll
        for (int ni = 0; ni < 4; ++ni) {
            int n = ni * 16 + r16;
            float4 f0 = *(const float4*)&Wsel[n * 64 + kk];
            float4 f1 = *(const float4*)&Wsel[n * 64 + kk + 4];
            short8 s;
            s[0] = (short)f2bf(f0.x); s[1] = (short)f2bf(f0.y);
            s[2] = (short)f2bf(f0.z); s[3] = (short)f2bf(f0.w);
            s[4] = (short)f2bf(f1.x); s[5] = (short)f2bf(f1.y);
            s[6] = (short)f2bf(f1.z); s[7] = (short)f2bf(f1.w);
            bfrag[ki][ni] = s;
        }
    }
    const float* bsel = nh ? bn : bp;
    float bias[4];
    #pragma unroll
    for (int ni = 0; ni < 4; ++ni) bias[ni] = bsel[ni * 16 + r16];

    int kbase = nh * 64;

    for (int tile = blockIdx.x; tile < ntiles; tile += gridDim.x) {
        int node0 = tile * 64;
        __syncthreads();
        for (int i = t; i < 64 * 24; i += 256) {
            int row = i / 24, c = i % 24;
            int node = node0 + row;
            if (node >= N) node = N - 1;
            *(int4*)&A[row][c * 8] = *(const int4*)&U[(size_t)node * 192 + c * 8];
        }
        __syncthreads();

        f32x4 acc[2][4];
        #pragma unroll
        for (int mi = 0; mi < 2; ++mi)
            #pragma unroll
            for (int ni = 0; ni < 4; ++ni) {
                f32x4 c4 = {bias[ni], bias[ni], bias[ni], bias[ni]};
                acc[mi][ni] = c4;
            }

        #pragma unroll
        for (int ki = 0; ki < 4; ++ki) {
            short8 a0 = *(const short8*)&A[mh * 32 + r16][kbase + ki * 32 + q * 8];
            short8 a1 = *(const short8*)&A[mh * 32 + 16 + r16][kbase + ki * 32 + q * 8];
            #pragma unroll
            for (int ni = 0; ni < 4; ++ni) {
                acc[0][ni] = __builtin_amdgcn_mfma_f32_16x16x32_bf16(
                    a0, bfrag[ki][ni], acc[0][ni], 0, 0, 0);
                acc[1][ni] = __builtin_amdgcn_mfma_f32_16x16x32_bf16(
                    a1, bfrag[ki][ni], acc[1][ni], 0, 0, 0);
            }
        }

        #pragma unroll
        for (int mi = 0; mi < 2; ++mi)
            #pragma unroll
            for (int ni = 0; ni < 4; ++ni)
                #pragma unroll
                for (int r = 0; r < 4; ++r) {
                    int node = node0 + mh * 32 + mi * 16 + q * 4 + r;
                    if (node < N)
                        out[(size_t)node * 128 + nh * 64 + ni * 16 + r16] =
                            acc[mi][ni][r];
                }
    }
}

// ===================== f32 fallback path (small ws / big N) =================
__global__ __launch_bounds__(256) void scatter_kernel(
    const int* __restrict__ ei, int E, const float* __restrict__ x,
    float* __restrict__ out, int col_off, float* __restrict__ cnt)
{
    long long gid = (long long)blockIdx.x * 256 + threadIdx.x;
    int e = (int)(gid >> 6);
    if (e >= E) return;
    int f = (int)(gid & 63);
    int s = ei[e], d = ei[E + e];
    atomicAdd(&out[d * 128 + col_off + f], x[s * FDIM + f]);
    if (f == 0) atomicAdd(&cnt[d], 1.0f);
}

__global__ __launch_bounds__(256) void scale_kernel(
    float* __restrict__ out, const float* __restrict__ cnt, int N)
{
    int idx = blockIdx.x * 256 + threadIdx.x;
    if (idx >= N * 128) return;
    int node = idx >> 7, col = idx & 127, half = col >> 6;
    out[idx] /= fmaxf(cnt[half * N + node], 1.f);
}

__global__ __launch_bounds__(256) void transform_f32_kernel(
    const float* __restrict__ x,
    const float* __restrict__ Wp, const float* __restrict__ Wpc, const float* __restrict__ bp,
    const float* __restrict__ Wn, const float* __restrict__ Wnc, const float* __restrict__ bn,
    int N, float* __restrict__ out)
{
    __shared__ float V[2][128][64];
    __shared__ float B[192][36];
    __shared__ float bias[128];
    int t = threadIdx.x;
    int node0 = blockIdx.x * 32;
    for (int i = t; i < 4096; i += 256) {
        int k = i >> 6, j = i & 63;
        V[0][k][j]      = Wp[j * 64 + k];
        V[0][64 + k][j] = Wpc[j * 64 + k];
        V[1][k][j]      = Wnc[j * 64 + k];
        V[1][64 + k][j] = Wn[j * 64 + k];
    }
    if (t < 64) { bias[t] = bp[t]; bias[64 + t] = bn[t]; }
    for (int i = t; i < 64 * 32; i += 256) {
        int k = i & 63, n = i >> 6;
        int node = node0 + n;
        if (node < N) {
            B[k][n]       = out[(size_t)node * 128 + k];
            B[64 + k][n]  = x[node * 64 + k];
            B[128 + k][n] = out[(size_t)node * 128 + 64 + k];
        }
    }
    __syncthreads();
    int jj = t & 31, nq = t >> 5;
    float acc[2][4][2];
    for (int h = 0; h < 2; ++h)
        for (int i = 0; i < 4; ++i) { acc[h][i][0] = 0.f; acc[h][i][1] = 0.f; }
    for (int h = 0; h < 2; ++h) {
        int browbase = h * 64;
        #pragma unroll 4
        for (int kk = 0; kk < 128; ++kk) {
            float2 v = *(const float2*)&V[h][kk][2 * jj];
            float4 b = *(const float4*)&B[browbase + kk][4 * nq];
            acc[h][0][0] += b.x * v.x;  acc[h][0][1] += b.x * v.y;
            acc[h][1][0] += b.y * v.x;  acc[h][1][1] += b.y * v.y;
            acc[h][2][0] += b.z * v.x;  acc[h][2][1] += b.z * v.y;
            acc[h][3][0] += b.w * v.x;  acc[h][3][1] += b.w * v.y;
        }
    }
    for (int h = 0; h < 2; ++h) {
        float bx = bias[h * 64 + 2 * jj], by = bias[h * 64 + 2 * jj + 1];
        for (int i = 0; i < 4; ++i) {
            int node = node0 + 4 * nq + i;
            if (node < N) {
                float2 r; r.x = acc[h][i][0] + bx; r.y = acc[h][i][1] + by;
                *(float2*)&out[(size_t)node * 128 + h * 64 + 2 * jj] = r;
            }
        }
    }
}

// ============================================================================
extern "C" void kernel_launch(void* const* d_in, const int* in_sizes, int n_in,
                              void* d_out, int out_size, void* d_ws, size_t ws_size,
                              hipStream_t stream) {
    const float* x   = (const float*)d_in[0];
    const int*   pei = (const int*)d_in[1];
    const int*   nei = (const int*)d_in[2];
    const float* Wp  = (const float*)d_in[3];
    const float* Wpc = (const float*)d_in[4];
    const float* bp  = (const float*)d_in[5];
    const float* Wn  = (const float*)d_in[6];
    const float* Wnc = (const float*)d_in[7];
    const float* bn  = (const float*)d_in[8];
    float* out = (float*)d_out;

    int N = in_sizes[0] / FDIM;
    int E = in_sizes[1] / 2;
    int twoE = 2 * E;
    int twoN = 2 * N;
    int nbuck = (twoN + BSEG - 1) / BSEG;
    int nA = (twoE + CHUNK - 1) / CHUNK;

    // ws ints: cntA[nA*nbuck] | colsum[nbuck] | bstart[nbuck+1] | P[2E] |
    //          soffs[2N] | sdeg[2N] | U (bf16)
    size_t ints = (size_t)nA * nbuck + nbuck + (nbuck + 1) + twoE + 2 * (size_t)twoN;
    size_t U_off = ((ints * 4 + 15) / 16) * 16;
    size_t need = U_off + (size_t)N * 192 * 2;

    if (ws_size >= need && nbuck <= MAXBUCK && N <= (1 << 17)) {
        int* cntA    = (int*)d_ws;
        int* colsum  = cntA + (size_t)nA * nbuck;
        int* bstart  = colsum + nbuck;
        unsigned* P  = (unsigned*)(bstart + nbuck + 1);
        int* soffs   = (int*)(P + twoE);
        int* sdeg    = soffs + twoN;
        ushort* U    = (ushort*)((char*)d_ws + U_off);

        prep_kernel<<<(N * 64 / 4 + 255) / 256, 256, 0, stream>>>(x, N, U);

        hist_bucket_kernel<<<nA, 1024, 0, stream>>>(pei, nei, E, N, nbuck, cntA);
        colscan_kernel<<<(nbuck + 255) / 256, 256, 0, stream>>>(cntA, nA, nbuck, colsum);
        scan_buckets_kernel<<<1, 256, 0, stream>>>(colsum, bstart, nbuck);
        place_bucket_kernel<<<nA, 1024, 0, stream>>>(pei, nei, E, N, nbuck, cntA, bstart, P);

        sort_bucket_kernel<<<nbuck, 256, 0, stream>>>(P, bstart, twoN, soffs, sdeg);

        agg_wide_kernel<<<(twoN + 3) / 4, 256, 0, stream>>>(P, soffs, sdeg, bstart, N, U);

        int ntiles = (N + 63) / 64;
        transform_mfma_kernel<<<768, 256, 0, stream>>>(
            U, Wp, Wpc, bp, Wn, Wnc, bn, N, ntiles, out);
    } else {
        float* cntf = (float*)d_ws;
        hipMemsetAsync(d_out, 0, (size_t)out_size * sizeof(float), stream);
        hipMemsetAsync(d_ws, 0, (size_t)twoN * sizeof(float), stream);
        int sblocks = (int)(((long long)E * 64 + 255) / 256);
        scatter_kernel<<<sblocks, 256, 0, stream>>>(pei, E, x, out, 0, cntf);
        scatter_kernel<<<sblocks, 256, 0, stream>>>(nei, E, x, out, 64, cntf + N);
        scale_kernel<<<(N * 128 + 255) / 256, 256, 0, stream>>>(out, cntf, N);
        transform_f32_kernel<<<(N + 31) / 32, 256, 0, stream>>>(
            x, Wp, Wpc, bp, Wn, Wnc, bn, N, out);
    }
}